// Round 1
// baseline (5518.117 us; speedup 1.0000x reference)
//
#include <hip/hip_runtime.h>
#include <float.h>
#include <math.h>

#define BB   4
#define NPTS 8192
#define MS   1024
#define DIM  768
#define NH   12
#define DHD  64
#define KNN  8
#define BMD  (BB*MS*DIM)

static __device__ __forceinline__ float sqdist3(float ax, float ay, float az,
                                                float bx, float by, float bz) {
  float dx = __fsub_rn(ax, bx);
  float dy = __fsub_rn(ay, by);
  float dz = __fsub_rn(az, bz);
  // match XLA: elementwise square (mul), then sequential sum — no fma contraction
  return __fadd_rn(__fadd_rn(__fmul_rn(dx, dx), __fmul_rn(dy, dy)), __fmul_rn(dz, dz));
}

// ---------------------------------------------------------------------------
// 1) Farthest point sampling: one block per batch, 1024 threads, 8 pts/thread
// ---------------------------------------------------------------------------
__global__ __launch_bounds__(1024) void fps_kernel(const float* __restrict__ points,
                                                   float* __restrict__ sampled) {
  const int b = blockIdx.x;
  const float* pts = points + (size_t)b * NPTS * 3;
  float* smp = sampled + (size_t)b * MS * 3;
  const int tid = threadIdx.x;
  const int lane = tid & 63, wid = tid >> 6;

  float px[8], py[8], pz[8], md[8];
  // start point = index 0 (matches reference idx0 = 0)
  const float qx = pts[0], qy = pts[1], qz = pts[2];
#pragma unroll
  for (int j = 0; j < 8; ++j) {
    int i = tid + j * 1024;
    px[j] = pts[i * 3 + 0];
    py[j] = pts[i * 3 + 1];
    pz[j] = pts[i * 3 + 2];
    md[j] = sqdist3(px[j], py[j], pz[j], qx, qy, qz);
  }
  if (tid == 0) { smp[0] = qx; smp[1] = qy; smp[2] = qz; }

  __shared__ float redv[2][16], redx[2][16], redy[2][16], redz[2][16];
  __shared__ int   redi[2][16];

  for (int s = 1; s < MS; ++s) {
    // local argmax over 8 (tie -> lower global index; j ascending == idx ascending)
    float bv = md[0]; int bj = 0;
#pragma unroll
    for (int j = 1; j < 8; ++j)
      if (md[j] > bv) { bv = md[j]; bj = j; }
    int   bidx = tid + bj * 1024;
    float bx = px[bj], by = py[bj], bz = pz[bj];

    // wave butterfly argmax carrying (v, idx, x, y, z); tie -> lower idx
#pragma unroll
    for (int off = 32; off >= 1; off >>= 1) {
      float ov = __shfl_xor(bv, off);
      int   oi = __shfl_xor(bidx, off);
      float ox = __shfl_xor(bx, off);
      float oy = __shfl_xor(by, off);
      float oz = __shfl_xor(bz, off);
      if (ov > bv || (ov == bv && oi < bidx)) { bv = ov; bidx = oi; bx = ox; by = oy; bz = oz; }
    }
    const int buf = s & 1;
    if (lane == 0) {
      redv[buf][wid] = bv; redi[buf][wid] = bidx;
      redx[buf][wid] = bx; redy[buf][wid] = by; redz[buf][wid] = bz;
    }
    __syncthreads();
    // every thread scans the 16 wave winners identically (broadcast LDS reads)
    bv = redv[buf][0]; bidx = redi[buf][0]; bx = redx[buf][0]; by = redy[buf][0]; bz = redz[buf][0];
#pragma unroll
    for (int w = 1; w < 16; ++w) {
      float ov = redv[buf][w]; int oi = redi[buf][w];
      if (ov > bv || (ov == bv && oi < bidx)) {
        bv = ov; bidx = oi; bx = redx[buf][w]; by = redy[buf][w]; bz = redz[buf][w];
      }
    }
    if (tid == 0) {
      smp[s * 3 + 0] = bx; smp[s * 3 + 1] = by; smp[s * 3 + 2] = bz;
    }
#pragma unroll
    for (int j = 0; j < 8; ++j) {
      float d = sqdist3(px[j], py[j], pz[j], bx, by, bz);
      md[j] = fminf(md[j], d);
    }
    // double-buffered LDS: no second sync needed
  }
}

// ---------------------------------------------------------------------------
// 2) Point embedding: feats = sampled @ W_embed + b_embed    [B*M, 768]
// ---------------------------------------------------------------------------
__global__ void embed_kernel(const float* __restrict__ sampled,
                             const float* __restrict__ W,
                             const float* __restrict__ bias,
                             float* __restrict__ out) {
  int idx = blockIdx.x * blockDim.x + threadIdx.x;
  if (idx >= BMD) return;
  int d = idx % DIM;
  int bm = idx / DIM;
  float x = sampled[bm * 3 + 0], y = sampled[bm * 3 + 1], z = sampled[bm * 3 + 2];
  out[idx] = fmaf(z, W[2 * DIM + d], fmaf(y, W[DIM + d], fmaf(x, W[d], bias[d])));
}

// ---------------------------------------------------------------------------
// 3) kNN (k=8, incl. self) + edge = feat - mean(neighbor feats)
//    one block per (b, m); 256 threads
// ---------------------------------------------------------------------------
__global__ __launch_bounds__(256) void knn_edge_kernel(const float* __restrict__ sampled,
                                                       const float* __restrict__ feats,
                                                       float* __restrict__ edge) {
  const int bm = blockIdx.x;
  const int b = bm >> 10, m = bm & 1023;
  const float* sp = sampled + (size_t)b * MS * 3;
  const int t = threadIdx.x, lane = t & 63, wid = t >> 6;

  __shared__ float dist[MS];
  __shared__ float redv[4];
  __shared__ int   redi[4];
  __shared__ int   win[KNN];

  const float qx = sp[m * 3 + 0], qy = sp[m * 3 + 1], qz = sp[m * 3 + 2];
#pragma unroll
  for (int j = 0; j < 4; ++j) {
    int i = t + j * 256;
    dist[i] = sqdist3(sp[i * 3 + 0], sp[i * 3 + 1], sp[i * 3 + 2], qx, qy, qz);
  }
  __syncthreads();

  for (int it = 0; it < KNN; ++it) {
    // local argmin over 4 (tie -> lower index)
    float bv = dist[t]; int bi = t;
#pragma unroll
    for (int j = 1; j < 4; ++j) {
      int i = t + j * 256;
      float v = dist[i];
      if (v < bv || (v == bv && i < bi)) { bv = v; bi = i; }
    }
#pragma unroll
    for (int off = 32; off >= 1; off >>= 1) {
      float ov = __shfl_xor(bv, off);
      int   oi = __shfl_xor(bi, off);
      if (ov < bv || (ov == bv && oi < bi)) { bv = ov; bi = oi; }
    }
    if (lane == 0) { redv[wid] = bv; redi[wid] = bi; }
    __syncthreads();
    if (t == 0) {
      float wv = redv[0]; int wi = redi[0];
#pragma unroll
      for (int w = 1; w < 4; ++w) {
        float ov = redv[w]; int oi = redi[w];
        if (ov < wv || (ov == wv && oi < wi)) { wv = ov; wi = oi; }
      }
      win[it] = wi;
      dist[wi] = FLT_MAX;
    }
    __syncthreads();
  }

  const float* fb = feats + (size_t)b * MS * DIM;
  float* eb = edge + (size_t)b * MS * DIM;
  for (int d = t; d < DIM; d += 256) {
    float acc = 0.f;
#pragma unroll
    for (int i = 0; i < KNN; ++i) acc += fb[(size_t)win[i] * DIM + d];
    eb[(size_t)m * DIM + d] = fb[(size_t)m * DIM + d] - acc * 0.125f;
  }
}

// ---------------------------------------------------------------------------
// 4) fp32 tiled GEMM: C[4096,768] = A[4096,768] @ W[768,768] + bias
//    MODE 1: also += sampled@Ws + bs (final epilogue)
// ---------------------------------------------------------------------------
template <int MODE>
__global__ __launch_bounds__(256) void gemm_kernel(const float* __restrict__ A,
                                                   const float* __restrict__ W,
                                                   const float* __restrict__ bias,
                                                   float* __restrict__ C,
                                                   const float* __restrict__ sampled,
                                                   const float* __restrict__ Ws,
                                                   const float* __restrict__ bs) {
  __shared__ float As[16][68];  // [k][m], padded for aligned float4 + low conflicts
  __shared__ float Bs[16][68];  // [k][n]

  const int t = threadIdx.x;
  const int tx = t & 15, ty = t >> 4;
  const int rowBase = blockIdx.x * 64;
  const int nBase = blockIdx.y * 64;

  float c[4][4] = {};

  const int ar = t >> 2, ac4 = (t & 3) * 4;    // A tile: 64 rows x 16 k
  const int br = t >> 4, bc4 = (t & 15) * 4;   // W tile: 16 k x 64 n

  for (int k0 = 0; k0 < DIM; k0 += 16) {
    float4 a = *(const float4*)&A[(size_t)(rowBase + ar) * DIM + k0 + ac4];
    As[ac4 + 0][ar] = a.x; As[ac4 + 1][ar] = a.y;
    As[ac4 + 2][ar] = a.z; As[ac4 + 3][ar] = a.w;
    float4 w = *(const float4*)&W[(size_t)(k0 + br) * DIM + nBase + bc4];
    *(float4*)&Bs[br][bc4] = w;
    __syncthreads();
#pragma unroll
    for (int k = 0; k < 16; ++k) {
      float av[4], bv[4];
      *(float4*)av = *(const float4*)&As[k][ty * 4];
      *(float4*)bv = *(const float4*)&Bs[k][tx * 4];
#pragma unroll
      for (int i = 0; i < 4; ++i)
#pragma unroll
        for (int j = 0; j < 4; ++j)
          c[i][j] = fmaf(av[i], bv[j], c[i][j]);
    }
    __syncthreads();
  }

#pragma unroll
  for (int i = 0; i < 4; ++i) {
    int row = rowBase + ty * 4 + i;
#pragma unroll
    for (int j = 0; j < 4; ++j) {
      int n = nBase + tx * 4 + j;
      float v = c[i][j] + bias[n];
      if (MODE == 1) {
        const float* sp = sampled + (size_t)row * 3;
        float spt = fmaf(sp[2], Ws[2 * DIM + n], fmaf(sp[1], Ws[DIM + n], fmaf(sp[0], Ws[n], bs[n])));
        v += spt;
      }
      C[(size_t)row * DIM + n] = v;
    }
  }
}

// ---------------------------------------------------------------------------
// 5) Flash attention: 1 wave per (b,h,row); K/V tiles (64x64) staged in LDS
// ---------------------------------------------------------------------------
__global__ __launch_bounds__(256) void attn_kernel(const float* __restrict__ Q,
                                                   const float* __restrict__ K,
                                                   const float* __restrict__ V,
                                                   float* __restrict__ O) {
  const int blk = blockIdx.x;                 // B*H*(M/4) blocks
  const int bh = blk / (MS / 4);
  const int rblk = blk % (MS / 4);
  const int b = bh / NH, h = bh % NH;
  const int t = threadIdx.x, lane = t & 63, wid = t >> 6;
  const int row = rblk * 4 + wid;

  __shared__ float Ks[64 * 65];
  __shared__ float Vs[64 * 65];

  const size_t headOff = (size_t)h * DHD;
  const float q = Q[((size_t)(b * MS + row)) * DIM + headOff + lane];

  float m_run = -INFINITY, l_run = 0.f, o = 0.f;

  for (int kt = 0; kt < MS / 64; ++kt) {
#pragma unroll
    for (int r = 0; r < 16; ++r) {
      int key = r * 4 + wid;
      size_t g = ((size_t)(b * MS + kt * 64 + key)) * DIM + headOff + lane;
      Ks[key * 65 + lane] = K[g];
      Vs[key * 65 + lane] = V[g];
    }
    __syncthreads();

    float s = 0.f;
#pragma unroll
    for (int k = 0; k < 64; ++k) {
      float qk = __shfl(q, k);
      s = fmaf(qk, Ks[lane * 65 + k], s);
    }
    s *= 0.125f;  // 1/sqrt(64)

    float mt = s;
#pragma unroll
    for (int off = 32; off >= 1; off >>= 1) mt = fmaxf(mt, __shfl_xor(mt, off));
    float m_new = fmaxf(m_run, mt);
    float corr = expf(m_run - m_new);  // m_run=-inf first tile -> corr=0
    float p = expf(s - m_new);
    float ps = p;
#pragma unroll
    for (int off = 32; off >= 1; off >>= 1) ps += __shfl_xor(ps, off);
    l_run = l_run * corr + ps;
    o *= corr;
#pragma unroll
    for (int j = 0; j < 64; ++j) {
      float pj = __shfl(p, j);
      o = fmaf(pj, Vs[j * 65 + lane], o);
    }
    m_run = m_new;
    __syncthreads();
  }

  O[((size_t)(b * MS + row)) * DIM + headOff + lane] = o / l_run;
}

// ---------------------------------------------------------------------------
extern "C" void kernel_launch(void* const* d_in, const int* in_sizes, int n_in,
                              void* d_out, int out_size, void* d_ws, size_t ws_size,
                              hipStream_t stream) {
  const float* points  = (const float*)d_in[0];
  const float* W_embed = (const float*)d_in[1];
  const float* b_embed = (const float*)d_in[2];
  const float* Wq = (const float*)d_in[3];
  const float* bq = (const float*)d_in[4];
  const float* Wk = (const float*)d_in[5];
  const float* bk = (const float*)d_in[6];
  const float* Wv = (const float*)d_in[7];
  const float* bv = (const float*)d_in[8];
  const float* Wo = (const float*)d_in[9];
  const float* bo = (const float*)d_in[10];
  const float* Ws = (const float*)d_in[11];
  const float* bs = (const float*)d_in[12];

  float* ws = (float*)d_ws;
  float* sampled = ws;                 // B*M*3 = 12288 (use 16384 slot)
  float* feats   = ws + 16384;         // BMD
  float* edge    = feats + BMD;
  float* qb      = edge + BMD;
  float* kb      = qb + BMD;
  float* vb      = kb + BMD;
  float* ao      = vb + BMD;

  fps_kernel<<<BB, 1024, 0, stream>>>(points, sampled);
  embed_kernel<<<(BMD + 255) / 256, 256, 0, stream>>>(sampled, W_embed, b_embed, feats);
  knn_edge_kernel<<<BB * MS, 256, 0, stream>>>(sampled, feats, edge);

  dim3 ggrid(4096 / 64, DIM / 64);
  gemm_kernel<0><<<ggrid, 256, 0, stream>>>(edge, Wq, bq, qb, nullptr, nullptr, nullptr);
  gemm_kernel<0><<<ggrid, 256, 0, stream>>>(edge, Wk, bk, kb, nullptr, nullptr, nullptr);
  gemm_kernel<0><<<ggrid, 256, 0, stream>>>(edge, Wv, bv, vb, nullptr, nullptr, nullptr);

  attn_kernel<<<BB * NH * (MS / 4), 256, 0, stream>>>(qb, kb, vb, ao);

  gemm_kernel<1><<<ggrid, 256, 0, stream>>>(ao, Wo, bo, (float*)d_out, sampled, Ws, bs);
}

// Round 5
// 2091.392 us; speedup vs baseline: 2.6385x; 2.6385x over previous
//
#include <hip/hip_runtime.h>
#include <float.h>
#include <math.h>

#define BB   4
#define NPTS 8192
#define MS   1024
#define DIM  768
#define NH   12
#define DHD  64
#define KNN  8
#define BMD  (BB*MS*DIM)

static __device__ __forceinline__ float sqdist3(float ax, float ay, float az,
                                                float bx, float by, float bz) {
  float dx = __fsub_rn(ax, bx);
  float dy = __fsub_rn(ay, by);
  float dz = __fsub_rn(az, bz);
  // match XLA: elementwise square (mul), then sequential sum — no fma contraction
  return __fadd_rn(__fadd_rn(__fmul_rn(dx, dx), __fmul_rn(dy, dy)), __fmul_rn(dz, dz));
}

// ---------------------------------------------------------------------------
// 1) FPS v2: one block/batch, 1024 threads, 8 pts/thread.
//    Argmax reduce carries ONE packed u64 (float bits << 32 | ~idx):
//    max => max dist, tie => lowest idx (matches jnp.argmax). Winner coords
//    come from an LDS coordinate cache (3 broadcast reads).
// ---------------------------------------------------------------------------
__global__ __launch_bounds__(1024) void fps_kernel(const float* __restrict__ points,
                                                   float* __restrict__ sampled) {
  const int b = blockIdx.x;
  const float* pts = points + (size_t)b * NPTS * 3;
  float* smp = sampled + (size_t)b * MS * 3;
  const int tid = threadIdx.x;
  const int lane = tid & 63, wid = tid >> 6;

  __shared__ float cxs[NPTS], cys[NPTS], czs[NPTS];     // 96 KB coord cache
  __shared__ unsigned long long red[2][16];

  float px[8], py[8], pz[8], md[8];
  const float qx0 = pts[0], qy0 = pts[1], qz0 = pts[2];
#pragma unroll
  for (int j = 0; j < 8; ++j) {
    int i = tid + j * 1024;
    float x = pts[i * 3 + 0], y = pts[i * 3 + 1], z = pts[i * 3 + 2];
    px[j] = x; py[j] = y; pz[j] = z;
    cxs[i] = x; cys[i] = y; czs[i] = z;
    md[j] = sqdist3(x, y, z, qx0, qy0, qz0);
  }
  if (tid == 0) { smp[0] = qx0; smp[1] = qy0; smp[2] = qz0; }
  __syncthreads();

  for (int s = 1; s < MS; ++s) {
    // local argmax over 8 (strict > keeps lowest j == lowest global idx)
    float bv = md[0]; int bj = 0;
#pragma unroll
    for (int j = 1; j < 8; ++j)
      if (md[j] > bv) { bv = md[j]; bj = j; }
    unsigned long long key =
        ((unsigned long long)__float_as_uint(bv) << 32) |
        (unsigned)(~(unsigned)(tid + bj * 1024));

    // wave butterfly max on packed key (2 shuffles/stage)
#pragma unroll
    for (int off = 1; off < 64; off <<= 1) {
      unsigned long long ok = __shfl_xor(key, off);
      if (ok > key) key = ok;
    }
    const int buf = s & 1;
    if (lane == 0) red[buf][wid] = key;
    __syncthreads();

    // depth-4 compare tree over 16 wave winners (broadcast LDS reads)
    unsigned long long kk[16];
#pragma unroll
    for (int i = 0; i < 16; ++i) kk[i] = red[buf][i];
#pragma unroll
    for (int st = 8; st >= 1; st >>= 1)
#pragma unroll
      for (int i = 0; i < 8; ++i)
        if (i < st && kk[i + st] > kk[i]) kk[i] = kk[i + st];

    const unsigned widx = ~(unsigned)(kk[0] & 0xffffffffull);
    const float wx = cxs[widx], wy = cys[widx], wz = czs[widx];
    if (tid == 0) {
      smp[s * 3 + 0] = wx; smp[s * 3 + 1] = wy; smp[s * 3 + 2] = wz;
    }
#pragma unroll
    for (int j = 0; j < 8; ++j) {
      float d = sqdist3(px[j], py[j], pz[j], wx, wy, wz);
      md[j] = fminf(md[j], d);
    }
    // double-buffered red[]: single barrier per iteration is safe
  }
}

// ---------------------------------------------------------------------------
// 2) Point embedding: feats = sampled @ W_embed + b_embed    [B*M, 768]
// ---------------------------------------------------------------------------
__global__ void embed_kernel(const float* __restrict__ sampled,
                             const float* __restrict__ W,
                             const float* __restrict__ bias,
                             float* __restrict__ out) {
  int idx = blockIdx.x * blockDim.x + threadIdx.x;
  if (idx >= BMD) return;
  int d = idx % DIM;
  int bm = idx / DIM;
  float x = sampled[bm * 3 + 0], y = sampled[bm * 3 + 1], z = sampled[bm * 3 + 2];
  out[idx] = fmaf(z, W[2 * DIM + d], fmaf(y, W[DIM + d], fmaf(x, W[d], bias[d])));
}

// ---------------------------------------------------------------------------
// 3) kNN (k=8, incl. self) + edge = feat - mean(neighbor feats)
// ---------------------------------------------------------------------------
__global__ __launch_bounds__(256) void knn_edge_kernel(const float* __restrict__ sampled,
                                                       const float* __restrict__ feats,
                                                       float* __restrict__ edge) {
  const int bm = blockIdx.x;
  const int b = bm >> 10, m = bm & 1023;
  const float* sp = sampled + (size_t)b * MS * 3;
  const int t = threadIdx.x, lane = t & 63, wid = t >> 6;

  __shared__ float dist[MS];
  __shared__ float redv[4];
  __shared__ int   redi[4];
  __shared__ int   win[KNN];

  const float qx = sp[m * 3 + 0], qy = sp[m * 3 + 1], qz = sp[m * 3 + 2];
#pragma unroll
  for (int j = 0; j < 4; ++j) {
    int i = t + j * 256;
    dist[i] = sqdist3(sp[i * 3 + 0], sp[i * 3 + 1], sp[i * 3 + 2], qx, qy, qz);
  }
  __syncthreads();

  for (int it = 0; it < KNN; ++it) {
    float bv = dist[t]; int bi = t;
#pragma unroll
    for (int j = 1; j < 4; ++j) {
      int i = t + j * 256;
      float v = dist[i];
      if (v < bv || (v == bv && i < bi)) { bv = v; bi = i; }
    }
#pragma unroll
    for (int off = 32; off >= 1; off >>= 1) {
      float ov = __shfl_xor(bv, off);
      int   oi = __shfl_xor(bi, off);
      if (ov < bv || (ov == bv && oi < bi)) { bv = ov; bi = oi; }
    }
    if (lane == 0) { redv[wid] = bv; redi[wid] = bi; }
    __syncthreads();
    if (t == 0) {
      float wv = redv[0]; int wi = redi[0];
#pragma unroll
      for (int w = 1; w < 4; ++w) {
        float ov = redv[w]; int oi = redi[w];
        if (ov < wv || (ov == wv && oi < wi)) { wv = ov; wi = oi; }
      }
      win[it] = wi;
      dist[wi] = FLT_MAX;
    }
    __syncthreads();
  }

  const float* fb = feats + (size_t)b * MS * DIM;
  float* eb = edge + (size_t)b * MS * DIM;
  for (int d = t; d < DIM; d += 256) {
    float acc = 0.f;
#pragma unroll
    for (int i = 0; i < KNN; ++i) acc += fb[(size_t)win[i] * DIM + d];
    eb[(size_t)m * DIM + d] = fb[(size_t)m * DIM + d] - acc * 0.125f;
  }
}

// ---------------------------------------------------------------------------
// 4) fp32 tiled GEMM: C[4096,768] = A[4096,768] @ W[768,768] + bias
//    MODE 1: also += sampled@Ws + bs (final epilogue)
// ---------------------------------------------------------------------------
template <int MODE>
__global__ __launch_bounds__(256) void gemm_kernel(const float* __restrict__ A,
                                                   const float* __restrict__ W,
                                                   const float* __restrict__ bias,
                                                   float* __restrict__ C,
                                                   const float* __restrict__ sampled,
                                                   const float* __restrict__ Ws,
                                                   const float* __restrict__ bs) {
  __shared__ float As[16][68];
  __shared__ float Bs[16][68];

  const int t = threadIdx.x;
  const int tx = t & 15, ty = t >> 4;
  const int rowBase = blockIdx.x * 64;
  const int nBase = blockIdx.y * 64;

  float c[4][4] = {};

  const int ar = t >> 2, ac4 = (t & 3) * 4;
  const int br = t >> 4, bc4 = (t & 15) * 4;

  for (int k0 = 0; k0 < DIM; k0 += 16) {
    float4 a = *(const float4*)&A[(size_t)(rowBase + ar) * DIM + k0 + ac4];
    As[ac4 + 0][ar] = a.x; As[ac4 + 1][ar] = a.y;
    As[ac4 + 2][ar] = a.z; As[ac4 + 3][ar] = a.w;
    float4 w = *(const float4*)&W[(size_t)(k0 + br) * DIM + nBase + bc4];
    *(float4*)&Bs[br][bc4] = w;
    __syncthreads();
#pragma unroll
    for (int k = 0; k < 16; ++k) {
      float av[4], bv[4];
      *(float4*)av = *(const float4*)&As[k][ty * 4];
      *(float4*)bv = *(const float4*)&Bs[k][tx * 4];
#pragma unroll
      for (int i = 0; i < 4; ++i)
#pragma unroll
        for (int j = 0; j < 4; ++j)
          c[i][j] = fmaf(av[i], bv[j], c[i][j]);
    }
    __syncthreads();
  }

#pragma unroll
  for (int i = 0; i < 4; ++i) {
    int row = rowBase + ty * 4 + i;
#pragma unroll
    for (int j = 0; j < 4; ++j) {
      int n = nBase + tx * 4 + j;
      float v = c[i][j] + bias[n];
      if (MODE == 1) {
        const float* sp = sampled + (size_t)row * 3;
        float spt = fmaf(sp[2], Ws[2 * DIM + n], fmaf(sp[1], Ws[DIM + n], fmaf(sp[0], Ws[n], bs[n])));
        v += spt;
      }
      C[(size_t)row * DIM + n] = v;
    }
  }
}

// ---------------------------------------------------------------------------
// 5) Attention v2: block = (b, h, 64-row tile), 4 waves; each wave owns 16
//    rows as a register-tiled GEMM (4x4 micro-tiles). XOR-swizzled LDS tiles
//    (<=2-way bank aliasing everywhere). Per-wave P buffer => 2 barriers/tile.
// ---------------------------------------------------------------------------
static __device__ __forceinline__ int lidx(int r, int c) {
  return r * 64 + (c ^ ((r & 7) << 2));
}

__global__ __launch_bounds__(256) void attn_kernel(const float* __restrict__ Q,
                                                   const float* __restrict__ K,
                                                   const float* __restrict__ V,
                                                   float* __restrict__ O) {
  const int nrt = MS / 64;                    // 16 row-tiles
  const int blk = blockIdx.x;                 // B*NH*nrt
  const int bh = blk / nrt, rt = blk % nrt;
  const int b = bh / NH, h = bh % NH;
  const int t = threadIdx.x, lane = t & 63, w = t >> 6;
  const int rg = lane >> 4, kg = lane & 15;

  __shared__ float Qs[64 * 64];
  __shared__ float Ks[64 * 64];
  __shared__ float Vs[64 * 64];
  __shared__ float Ps[4 * 16 * 64];           // per-wave private P

  const size_t base = (size_t)(b * MS) * DIM + (size_t)h * DHD;

  // stage Q tile (float4, swizzled)
#pragma unroll
  for (int i = 0; i < 4; ++i) {
    int f = t + i * 256;
    int r = f >> 4, c4 = (f & 15) * 4;
    *(float4*)&Qs[lidx(r, c4)] = *(const float4*)&Q[base + (size_t)(rt * 64 + r) * DIM + c4];
  }

  float m[4], l[4], o[4][4];
#pragma unroll
  for (int i = 0; i < 4; ++i) {
    m[i] = -INFINITY; l[i] = 0.f;
#pragma unroll
    for (int j = 0; j < 4; ++j) o[i][j] = 0.f;
  }

  const int lrow = w * 16 + rg * 4;           // block-local first row of this lane
  float* Pw = &Ps[w * 16 * 64];

  for (int kt = 0; kt < nrt; ++kt) {
#pragma unroll
    for (int i = 0; i < 4; ++i) {
      int f = t + i * 256;
      int r = f >> 4, c4 = (f & 15) * 4;
      size_t g = base + (size_t)(kt * 64 + r) * DIM + c4;
      *(float4*)&Ks[lidx(r, c4)] = *(const float4*)&K[g];
      *(float4*)&Vs[lidx(r, c4)] = *(const float4*)&V[g];
    }
    __syncthreads();

    // S[16x64] = Q_tile · K_tile^T  (keys per lane: kg + 16j)
    float s[4][4] = {};
#pragma unroll 8
    for (int d = 0; d < 64; ++d) {
      float a[4], bb[4];
#pragma unroll
      for (int i = 0; i < 4; ++i) a[i] = Qs[lidx(lrow + i, d)];
#pragma unroll
      for (int j = 0; j < 4; ++j) bb[j] = Ks[lidx(kg + 16 * j, d)];
#pragma unroll
      for (int i = 0; i < 4; ++i)
#pragma unroll
        for (int j = 0; j < 4; ++j) s[i][j] = fmaf(a[i], bb[j], s[i][j]);
    }

    // online softmax per row (replicated across the 16 kg-lanes of each rg)
#pragma unroll
    for (int i = 0; i < 4; ++i) {
#pragma unroll
      for (int j = 0; j < 4; ++j) s[i][j] *= 0.125f;   // 1/sqrt(64)
      float mt = fmaxf(fmaxf(s[i][0], s[i][1]), fmaxf(s[i][2], s[i][3]));
#pragma unroll
      for (int off = 1; off < 16; off <<= 1) mt = fmaxf(mt, __shfl_xor(mt, off));
      float mn = fmaxf(m[i], mt);
      float corr = expf(m[i] - mn);                    // -inf first tile -> 0
      float ps = 0.f;
#pragma unroll
      for (int j = 0; j < 4; ++j) { s[i][j] = expf(s[i][j] - mn); ps += s[i][j]; }
#pragma unroll
      for (int off = 1; off < 16; off <<= 1) ps += __shfl_xor(ps, off);
      l[i] = l[i] * corr + ps;
      m[i] = mn;
#pragma unroll
      for (int j = 0; j < 4; ++j) o[i][j] *= corr;
#pragma unroll
      for (int j = 0; j < 4; ++j) Pw[lidx(rg * 4 + i, kg + 16 * j)] = s[i][j];
    }
    // same-wave LDS RAW on Pw: compiler inserts lgkmcnt wait; no barrier needed

    // O[16x64] += P · V_tile   (columns per lane: kg + 16j)
#pragma unroll 8
    for (int k = 0; k < 64; ++k) {
      float a[4], bb[4];
#pragma unroll
      for (int i = 0; i < 4; ++i) a[i] = Pw[lidx(rg * 4 + i, k)];
#pragma unroll
      for (int j = 0; j < 4; ++j) bb[j] = Vs[lidx(k, kg + 16 * j)];
#pragma unroll
      for (int i = 0; i < 4; ++i)
#pragma unroll
        for (int j = 0; j < 4; ++j) o[i][j] = fmaf(a[i], bb[j], o[i][j]);
    }
    __syncthreads();   // protect Ks/Vs before next tile's staging
  }

#pragma unroll
  for (int i = 0; i < 4; ++i) {
    int row = rt * 64 + lrow + i;
#pragma unroll
    for (int j = 0; j < 4; ++j)
      O[base + (size_t)row * DIM + kg + 16 * j] = o[i][j] / l[i];
  }
}

// ---------------------------------------------------------------------------
extern "C" void kernel_launch(void* const* d_in, const int* in_sizes, int n_in,
                              void* d_out, int out_size, void* d_ws, size_t ws_size,
                              hipStream_t stream) {
  const float* points  = (const float*)d_in[0];
  const float* W_embed = (const float*)d_in[1];
  const float* b_embed = (const float*)d_in[2];
  const float* Wq = (const float*)d_in[3];
  const float* bq = (const float*)d_in[4];
  const float* Wk = (const float*)d_in[5];
  const float* bk = (const float*)d_in[6];
  const float* Wv = (const float*)d_in[7];
  const float* bv = (const float*)d_in[8];
  const float* Wo = (const float*)d_in[9];
  const float* bo = (const float*)d_in[10];
  const float* Ws = (const float*)d_in[11];
  const float* bs = (const float*)d_in[12];

  float* ws = (float*)d_ws;
  float* sampled = ws;                 // B*M*3
  float* feats   = ws + 16384;
  float* edge    = feats + BMD;
  float* qb      = edge + BMD;
  float* kb      = qb + BMD;
  float* vb      = kb + BMD;
  float* ao      = vb + BMD;

  fps_kernel<<<BB, 1024, 0, stream>>>(points, sampled);
  embed_kernel<<<(BMD + 255) / 256, 256, 0, stream>>>(sampled, W_embed, b_embed, feats);
  knn_edge_kernel<<<BB * MS, 256, 0, stream>>>(sampled, feats, edge);

  dim3 ggrid(4096 / 64, DIM / 64);
  gemm_kernel<0><<<ggrid, 256, 0, stream>>>(edge, Wq, bq, qb, nullptr, nullptr, nullptr);
  gemm_kernel<0><<<ggrid, 256, 0, stream>>>(edge, Wk, bk, kb, nullptr, nullptr, nullptr);
  gemm_kernel<0><<<ggrid, 256, 0, stream>>>(edge, Wv, bv, vb, nullptr, nullptr, nullptr);

  attn_kernel<<<BB * NH * (MS / 64), 256, 0, stream>>>(qb, kb, vb, ao);

  gemm_kernel<1><<<ggrid, 256, 0, stream>>>(ao, Wo, bo, (float*)d_out, sampled, Ws, bs);
}

// Round 11
// 1832.748 us; speedup vs baseline: 3.0108x; 1.1411x over previous
//
#include <hip/hip_runtime.h>
#include <float.h>
#include <math.h>

#define BB   4
#define NPTS 8192
#define MS   1024
#define DIM  768
#define NH   12
#define DHD  64
#define KNN  8
#define BMD  (BB*MS*DIM)

static __device__ __forceinline__ float sqdist3(float ax, float ay, float az,
                                                float bx, float by, float bz) {
  float dx = __fsub_rn(ax, bx);
  float dy = __fsub_rn(ay, by);
  float dz = __fsub_rn(az, bz);
  // match XLA: elementwise square (mul), then sequential sum — no fma contraction
  return __fadd_rn(__fadd_rn(__fmul_rn(dx, dx), __fmul_rn(dy, dy)), __fmul_rn(dz, dz));
}

// ---------------------------------------------------------------------------
// 1) FPS v3: one block/batch, 256 threads, 32 pts/thread.
//    Wave argmax via 6-stage DPP merge network (VALU latency, no ds_permute):
//    quad_perm[1,0,3,2], quad_perm[2,3,0,1], row_half_mirror, row_mirror,
//    row_bcast15, row_bcast31 -> lane63 holds wave winner. Merge op =
//    lexicographic max on packed u64 (distbits<<32 | ~idx) => exact argmax,
//    tie -> lowest idx (matches jnp.argmax). Cross-wave: 4 keys via LDS,
//    winner coords via one broadcast ds_read_b128 from a float4 LDS cache.
// ---------------------------------------------------------------------------
#define DPP_STAGE(key, ctrl)                                                   \
  {                                                                            \
    unsigned hi_ = (unsigned)((key) >> 32), lo_ = (unsigned)(key);             \
    unsigned nhi_ = (unsigned)__builtin_amdgcn_update_dpp(                     \
        (int)hi_, (int)hi_, (ctrl), 0xf, 0xf, false);                          \
    unsigned nlo_ = (unsigned)__builtin_amdgcn_update_dpp(                     \
        (int)lo_, (int)lo_, (ctrl), 0xf, 0xf, false);                          \
    unsigned long long nk_ = ((unsigned long long)nhi_ << 32) | nlo_;          \
    if (nk_ > (key)) (key) = nk_;                                              \
  }

__global__ __launch_bounds__(256, 1) void fps_kernel(const float* __restrict__ points,
                                                     float* __restrict__ sampled) {
  const int b = blockIdx.x;
  const float* pts = points + (size_t)b * NPTS * 3;
  float* smp = sampled + (size_t)b * MS * 3;
  const int tid = threadIdx.x;
  const int lane = tid & 63, w = tid >> 6;

  __shared__ float4 cxyz[NPTS];                     // 128 KB coord cache
  __shared__ unsigned long long red[2][4];

  float px[32], py[32], pz[32], md[32];
  const float qx0 = pts[0], qy0 = pts[1], qz0 = pts[2];

  float bv = -INFINITY;
  int bidx = 0;
#pragma unroll
  for (int j = 0; j < 32; ++j) {
    int i = tid + j * 256;
    float x = pts[i * 3 + 0], y = pts[i * 3 + 1], z = pts[i * 3 + 2];
    px[j] = x; py[j] = y; pz[j] = z;
    cxyz[i] = make_float4(x, y, z, 0.f);
    float d = sqdist3(x, y, z, qx0, qy0, qz0);
    md[j] = d;
    if (d > bv) { bv = d; bidx = i; }               // j ascending => lowest idx on tie
  }
  if (tid == 0) { smp[0] = qx0; smp[1] = qy0; smp[2] = qz0; }
  __syncthreads();

  for (int s = 1; s < MS; ++s) {
    // pack (dist, ~idx); non-negative float bits compare as uint
    unsigned long long key =
        ((unsigned long long)__float_as_uint(bv) << 32) |
        (unsigned)(~(unsigned)bidx);

    // 6-stage DPP merge network -> lane63 = wave winner
    DPP_STAGE(key, 0xB1);   // quad_perm [1,0,3,2]  (xor 1)
    DPP_STAGE(key, 0x4E);   // quad_perm [2,3,0,1]  (xor 2)
    DPP_STAGE(key, 0x141);  // row_half_mirror      (xor 7 within 8)
    DPP_STAGE(key, 0x140);  // row_mirror           (xor 15 within 16)
    DPP_STAGE(key, 0x142);  // row_bcast15          (row0->row1, row2->row3)
    DPP_STAGE(key, 0x143);  // row_bcast31          (lower32 -> upper32)

    const int buf = s & 1;
    if (lane == 63) red[buf][w] = key;
    __syncthreads();

    unsigned long long k0 = red[buf][0], k1 = red[buf][1];
    unsigned long long k2 = red[buf][2], k3 = red[buf][3];
    unsigned long long a = (k0 > k1) ? k0 : k1;
    unsigned long long c = (k2 > k3) ? k2 : k3;
    unsigned long long fk = (a > c) ? a : c;
    const unsigned widx = ~(unsigned)(fk & 0xffffffffull);

    const float4 wc = cxyz[widx];                   // one broadcast b128 read
    if (tid == 0) {
      smp[s * 3 + 0] = wc.x; smp[s * 3 + 1] = wc.y; smp[s * 3 + 2] = wc.z;
    }

    // fused md update + local argmax for next iteration
    bv = -INFINITY; bidx = 0;
#pragma unroll
    for (int j = 0; j < 32; ++j) {
      int i = tid + j * 256;
      float d = sqdist3(px[j], py[j], pz[j], wc.x, wc.y, wc.z);
      float nm = fminf(md[j], d);
      md[j] = nm;
      if (nm > bv) { bv = nm; bidx = i; }
    }
    // double-buffered red[]: one barrier per iteration is safe
  }
}

// ---------------------------------------------------------------------------
// 2) Point embedding: feats = sampled @ W_embed + b_embed    [B*M, 768]
// ---------------------------------------------------------------------------
__global__ void embed_kernel(const float* __restrict__ sampled,
                             const float* __restrict__ W,
                             const float* __restrict__ bias,
                             float* __restrict__ out) {
  int idx = blockIdx.x * blockDim.x + threadIdx.x;
  if (idx >= BMD) return;
  int d = idx % DIM;
  int bm = idx / DIM;
  float x = sampled[bm * 3 + 0], y = sampled[bm * 3 + 1], z = sampled[bm * 3 + 2];
  out[idx] = fmaf(z, W[2 * DIM + d], fmaf(y, W[DIM + d], fmaf(x, W[d], bias[d])));
}

// ---------------------------------------------------------------------------
// 3) kNN (k=8, incl. self) + edge = feat - mean(neighbor feats)
// ---------------------------------------------------------------------------
__global__ __launch_bounds__(256) void knn_edge_kernel(const float* __restrict__ sampled,
                                                       const float* __restrict__ feats,
                                                       float* __restrict__ edge) {
  const int bm = blockIdx.x;
  const int b = bm >> 10, m = bm & 1023;
  const float* sp = sampled + (size_t)b * MS * 3;
  const int t = threadIdx.x, lane = t & 63, wid = t >> 6;

  __shared__ float dist[MS];
  __shared__ float redv[4];
  __shared__ int   redi[4];
  __shared__ int   win[KNN];

  const float qx = sp[m * 3 + 0], qy = sp[m * 3 + 1], qz = sp[m * 3 + 2];
#pragma unroll
  for (int j = 0; j < 4; ++j) {
    int i = t + j * 256;
    dist[i] = sqdist3(sp[i * 3 + 0], sp[i * 3 + 1], sp[i * 3 + 2], qx, qy, qz);
  }
  __syncthreads();

  for (int it = 0; it < KNN; ++it) {
    float bv = dist[t]; int bi = t;
#pragma unroll
    for (int j = 1; j < 4; ++j) {
      int i = t + j * 256;
      float v = dist[i];
      if (v < bv || (v == bv && i < bi)) { bv = v; bi = i; }
    }
#pragma unroll
    for (int off = 32; off >= 1; off >>= 1) {
      float ov = __shfl_xor(bv, off);
      int   oi = __shfl_xor(bi, off);
      if (ov < bv || (ov == bv && oi < bi)) { bv = ov; bi = oi; }
    }
    if (lane == 0) { redv[wid] = bv; redi[wid] = bi; }
    __syncthreads();
    if (t == 0) {
      float wv = redv[0]; int wi = redi[0];
#pragma unroll
      for (int w = 1; w < 4; ++w) {
        float ov = redv[w]; int oi = redi[w];
        if (ov < wv || (ov == wv && oi < wi)) { wv = ov; wi = oi; }
      }
      win[it] = wi;
      dist[wi] = FLT_MAX;
    }
    __syncthreads();
  }

  const float* fb = feats + (size_t)b * MS * DIM;
  float* eb = edge + (size_t)b * MS * DIM;
  for (int d = t; d < DIM; d += 256) {
    float acc = 0.f;
#pragma unroll
    for (int i = 0; i < KNN; ++i) acc += fb[(size_t)win[i] * DIM + d];
    eb[(size_t)m * DIM + d] = fb[(size_t)m * DIM + d] - acc * 0.125f;
  }
}

// ---------------------------------------------------------------------------
// 4) fp32 tiled GEMM v2: C[4096,768] = A @ W + bias. 128x64 tile, 8x4 micro.
//    MODE 1: also += sampled@Ws + bs (final epilogue)
// ---------------------------------------------------------------------------
template <int MODE>
__global__ __launch_bounds__(256) void gemm_kernel(const float* __restrict__ A,
                                                   const float* __restrict__ W,
                                                   const float* __restrict__ bias,
                                                   float* __restrict__ C,
                                                   const float* __restrict__ sampled,
                                                   const float* __restrict__ Ws,
                                                   const float* __restrict__ bs) {
  __shared__ float As[16][132];   // [k][m], padded
  __shared__ float Bs[16][68];    // [k][n], padded

  const int t = threadIdx.x;
  const int tx = t & 15, ty = t >> 4;      // tx: n/4, ty: m/8
  const int rowBase = blockIdx.x * 128;
  const int nBase = blockIdx.y * 64;

  float c[8][4] = {};

  const int ar = t >> 1, ac8 = (t & 1) * 8;   // A: 128 rows x 16 k, 2 float4/thread
  const int br = t >> 4, bc4 = (t & 15) * 4;  // B: 16 k x 64 n, 1 float4/thread

  for (int k0 = 0; k0 < DIM; k0 += 16) {
    float4 a0 = *(const float4*)&A[(size_t)(rowBase + ar) * DIM + k0 + ac8];
    float4 a1 = *(const float4*)&A[(size_t)(rowBase + ar) * DIM + k0 + ac8 + 4];
    As[ac8 + 0][ar] = a0.x; As[ac8 + 1][ar] = a0.y;
    As[ac8 + 2][ar] = a0.z; As[ac8 + 3][ar] = a0.w;
    As[ac8 + 4][ar] = a1.x; As[ac8 + 5][ar] = a1.y;
    As[ac8 + 6][ar] = a1.z; As[ac8 + 7][ar] = a1.w;
    float4 wv = *(const float4*)&W[(size_t)(k0 + br) * DIM + nBase + bc4];
    *(float4*)&Bs[br][bc4] = wv;
    __syncthreads();
#pragma unroll
    for (int k = 0; k < 16; ++k) {
      float av[8], bv[4];
      *(float4*)&av[0] = *(const float4*)&As[k][ty * 8];
      *(float4*)&av[4] = *(const float4*)&As[k][ty * 8 + 4];
      *(float4*)bv = *(const float4*)&Bs[k][tx * 4];
#pragma unroll
      for (int i = 0; i < 8; ++i)
#pragma unroll
        for (int j = 0; j < 4; ++j)
          c[i][j] = fmaf(av[i], bv[j], c[i][j]);
    }
    __syncthreads();
  }

#pragma unroll
  for (int i = 0; i < 8; ++i) {
    int row = rowBase + ty * 8 + i;
#pragma unroll
    for (int j = 0; j < 4; ++j) {
      int n = nBase + tx * 4 + j;
      float v = c[i][j] + bias[n];
      if (MODE == 1) {
        const float* sp = sampled + (size_t)row * 3;
        float spt = fmaf(sp[2], Ws[2 * DIM + n], fmaf(sp[1], Ws[DIM + n], fmaf(sp[0], Ws[n], bs[n])));
        v += spt;
      }
      C[(size_t)row * DIM + n] = v;
    }
  }
}

// ---------------------------------------------------------------------------
// 5) Attention v2 (unchanged): 64-row tile, 4 waves, 4x4 register micro-tiles,
//    XOR-swizzled LDS, per-wave P buffer, 2 barriers/tile.
// ---------------------------------------------------------------------------
static __device__ __forceinline__ int lidx(int r, int c) {
  return r * 64 + (c ^ ((r & 7) << 2));
}

__global__ __launch_bounds__(256) void attn_kernel(const float* __restrict__ Q,
                                                   const float* __restrict__ K,
                                                   const float* __restrict__ V,
                                                   float* __restrict__ O) {
  const int nrt = MS / 64;                    // 16 row-tiles
  const int blk = blockIdx.x;                 // B*NH*nrt
  const int bh = blk / nrt, rt = blk % nrt;
  const int b = bh / NH, h = bh % NH;
  const int t = threadIdx.x, lane = t & 63, w = t >> 6;
  const int rg = lane >> 4, kg = lane & 15;

  __shared__ float Qs[64 * 64];
  __shared__ float Ks[64 * 64];
  __shared__ float Vs[64 * 64];
  __shared__ float Ps[4 * 16 * 64];           // per-wave private P

  const size_t base = (size_t)(b * MS) * DIM + (size_t)h * DHD;

#pragma unroll
  for (int i = 0; i < 4; ++i) {
    int f = t + i * 256;
    int r = f >> 4, c4 = (f & 15) * 4;
    *(float4*)&Qs[lidx(r, c4)] = *(const float4*)&Q[base + (size_t)(rt * 64 + r) * DIM + c4];
  }

  float m[4], l[4], o[4][4];
#pragma unroll
  for (int i = 0; i < 4; ++i) {
    m[i] = -INFINITY; l[i] = 0.f;
#pragma unroll
    for (int j = 0; j < 4; ++j) o[i][j] = 0.f;
  }

  const int lrow = w * 16 + rg * 4;
  float* Pw = &Ps[w * 16 * 64];

  for (int kt = 0; kt < nrt; ++kt) {
#pragma unroll
    for (int i = 0; i < 4; ++i) {
      int f = t + i * 256;
      int r = f >> 4, c4 = (f & 15) * 4;
      size_t g = base + (size_t)(kt * 64 + r) * DIM + c4;
      *(float4*)&Ks[lidx(r, c4)] = *(const float4*)&K[g];
      *(float4*)&Vs[lidx(r, c4)] = *(const float4*)&V[g];
    }
    __syncthreads();

    float s[4][4] = {};
#pragma unroll 8
    for (int d = 0; d < 64; ++d) {
      float a[4], bb[4];
#pragma unroll
      for (int i = 0; i < 4; ++i) a[i] = Qs[lidx(lrow + i, d)];
#pragma unroll
      for (int j = 0; j < 4; ++j) bb[j] = Ks[lidx(kg + 16 * j, d)];
#pragma unroll
      for (int i = 0; i < 4; ++i)
#pragma unroll
        for (int j = 0; j < 4; ++j) s[i][j] = fmaf(a[i], bb[j], s[i][j]);
    }

#pragma unroll
    for (int i = 0; i < 4; ++i) {
#pragma unroll
      for (int j = 0; j < 4; ++j) s[i][j] *= 0.125f;   // 1/sqrt(64)
      float mt = fmaxf(fmaxf(s[i][0], s[i][1]), fmaxf(s[i][2], s[i][3]));
#pragma unroll
      for (int off = 1; off < 16; off <<= 1) mt = fmaxf(mt, __shfl_xor(mt, off));
      float mn = fmaxf(m[i], mt);
      float corr = expf(m[i] - mn);
      float ps = 0.f;
#pragma unroll
      for (int j = 0; j < 4; ++j) { s[i][j] = expf(s[i][j] - mn); ps += s[i][j]; }
#pragma unroll
      for (int off = 1; off < 16; off <<= 1) ps += __shfl_xor(ps, off);
      l[i] = l[i] * corr + ps;
      m[i] = mn;
#pragma unroll
      for (int j = 0; j < 4; ++j) o[i][j] *= corr;
#pragma unroll
      for (int j = 0; j < 4; ++j) Pw[lidx(rg * 4 + i, kg + 16 * j)] = s[i][j];
    }

#pragma unroll 8
    for (int k = 0; k < 64; ++k) {
      float a[4], bb[4];
#pragma unroll
      for (int i = 0; i < 4; ++i) a[i] = Pw[lidx(rg * 4 + i, k)];
#pragma unroll
      for (int j = 0; j < 4; ++j) bb[j] = Vs[lidx(k, kg + 16 * j)];
#pragma unroll
      for (int i = 0; i < 4; ++i)
#pragma unroll
        for (int j = 0; j < 4; ++j) o[i][j] = fmaf(a[i], bb[j], o[i][j]);
    }
    __syncthreads();
  }

#pragma unroll
  for (int i = 0; i < 4; ++i) {
    int row = rt * 64 + lrow + i;
#pragma unroll
    for (int j = 0; j < 4; ++j)
      O[base + (size_t)row * DIM + kg + 16 * j] = o[i][j] / l[i];
  }
}

// ---------------------------------------------------------------------------
extern "C" void kernel_launch(void* const* d_in, const int* in_sizes, int n_in,
                              void* d_out, int out_size, void* d_ws, size_t ws_size,
                              hipStream_t stream) {
  const float* points  = (const float*)d_in[0];
  const float* W_embed = (const float*)d_in[1];
  const float* b_embed = (const float*)d_in[2];
  const float* Wq = (const float*)d_in[3];
  const float* bq = (const float*)d_in[4];
  const float* Wk = (const float*)d_in[5];
  const float* bk = (const float*)d_in[6];
  const float* Wv = (const float*)d_in[7];
  const float* bv = (const float*)d_in[8];
  const float* Wo = (const float*)d_in[9];
  const float* bo = (const float*)d_in[10];
  const float* Ws = (const float*)d_in[11];
  const float* bs = (const float*)d_in[12];

  float* ws = (float*)d_ws;
  float* sampled = ws;                 // B*M*3
  float* feats   = ws + 16384;
  float* edge    = feats + BMD;
  float* qb      = edge + BMD;
  float* kb      = qb + BMD;
  float* vb      = kb + BMD;
  float* ao      = vb + BMD;

  fps_kernel<<<BB, 256, 0, stream>>>(points, sampled);
  embed_kernel<<<(BMD + 255) / 256, 256, 0, stream>>>(sampled, W_embed, b_embed, feats);
  knn_edge_kernel<<<BB * MS, 256, 0, stream>>>(sampled, feats, edge);

  dim3 ggrid(4096 / 128, DIM / 64);
  gemm_kernel<0><<<ggrid, 256, 0, stream>>>(edge, Wq, bq, qb, nullptr, nullptr, nullptr);
  gemm_kernel<0><<<ggrid, 256, 0, stream>>>(edge, Wk, bk, kb, nullptr, nullptr, nullptr);
  gemm_kernel<0><<<ggrid, 256, 0, stream>>>(edge, Wv, bv, vb, nullptr, nullptr, nullptr);

  attn_kernel<<<BB * NH * (MS / 64), 256, 0, stream>>>(qb, kb, vb, ao);

  gemm_kernel<1><<<ggrid, 256, 0, stream>>>(ao, Wo, bo, (float*)d_out, sampled, Ws, bs);
}

// Round 13
// 1783.315 us; speedup vs baseline: 3.0943x; 1.0277x over previous
//
#include <hip/hip_runtime.h>
#include <float.h>
#include <math.h>

#define BB   4
#define NPTS 8192
#define MS   1024
#define DIM  768
#define NH   12
#define DHD  64
#define KNN  8
#define BMD  (BB*MS*DIM)

static __device__ __forceinline__ float sqdist3(float ax, float ay, float az,
                                                float bx, float by, float bz) {
  float dx = __fsub_rn(ax, bx);
  float dy = __fsub_rn(ay, by);
  float dz = __fsub_rn(az, bz);
  // match XLA: elementwise square (mul), then sequential sum — no fma contraction
  return __fadd_rn(__fadd_rn(__fmul_rn(dx, dx), __fmul_rn(dy, dy)), __fmul_rn(dz, dz));
}

// ---------------------------------------------------------------------------
// 1) FPS v4: one block/batch, 512 threads, 16 pts/thread (v3 was 256x32 and
//    needed 128 VGPRs of arrays at VGPR_Count=132 -> spill risk; 16/thread
//    needs 64 and runs 2 waves/SIMD for serial-chain overlap).
//    Wave argmax via 6-stage DPP merge network on packed u64
//    (distbits<<32 | ~idx): max => max dist, tie -> lowest idx (jnp.argmax).
//    Cross-wave: 8 keys via LDS; winner coords via one broadcast
//    ds_read_b128 from a float4 LDS cache.
// ---------------------------------------------------------------------------
#define DPP_STAGE(key, ctrl)                                                   \
  {                                                                            \
    unsigned hi_ = (unsigned)((key) >> 32), lo_ = (unsigned)(key);             \
    unsigned nhi_ = (unsigned)__builtin_amdgcn_update_dpp(                     \
        (int)hi_, (int)hi_, (ctrl), 0xf, 0xf, false);                          \
    unsigned nlo_ = (unsigned)__builtin_amdgcn_update_dpp(                     \
        (int)lo_, (int)lo_, (ctrl), 0xf, 0xf, false);                          \
    unsigned long long nk_ = ((unsigned long long)nhi_ << 32) | nlo_;          \
    if (nk_ > (key)) (key) = nk_;                                              \
  }

__global__ __launch_bounds__(512, 1) void fps_kernel(const float* __restrict__ points,
                                                     float* __restrict__ sampled) {
  const int b = blockIdx.x;
  const float* pts = points + (size_t)b * NPTS * 3;
  float* smp = sampled + (size_t)b * MS * 3;
  const int tid = threadIdx.x;
  const int lane = tid & 63, w = tid >> 6;

  __shared__ float4 cxyz[NPTS];                     // 128 KB coord cache
  __shared__ unsigned long long red[2][8];

  float px[16], py[16], pz[16], md[16];
  const float qx0 = pts[0], qy0 = pts[1], qz0 = pts[2];

  float bv = -INFINITY;
  int bidx = 0;
#pragma unroll
  for (int j = 0; j < 16; ++j) {
    int i = tid + j * 512;
    float x = pts[i * 3 + 0], y = pts[i * 3 + 1], z = pts[i * 3 + 2];
    px[j] = x; py[j] = y; pz[j] = z;
    cxyz[i] = make_float4(x, y, z, 0.f);
    float d = sqdist3(x, y, z, qx0, qy0, qz0);
    md[j] = d;
    if (d > bv) { bv = d; bidx = i; }               // j ascending => lowest idx on tie
  }
  if (tid == 0) { smp[0] = qx0; smp[1] = qy0; smp[2] = qz0; }
  __syncthreads();

  for (int s = 1; s < MS; ++s) {
    // pack (dist, ~idx); non-negative float bits compare as uint
    unsigned long long key =
        ((unsigned long long)__float_as_uint(bv) << 32) |
        (unsigned)(~(unsigned)bidx);

    // 6-stage DPP merge network -> lane63 = wave winner
    DPP_STAGE(key, 0xB1);   // quad_perm [1,0,3,2]  (xor 1)
    DPP_STAGE(key, 0x4E);   // quad_perm [2,3,0,1]  (xor 2)
    DPP_STAGE(key, 0x141);  // row_half_mirror      (xor 7 within 8)
    DPP_STAGE(key, 0x140);  // row_mirror           (xor 15 within 16)
    DPP_STAGE(key, 0x142);  // row_bcast15          (row0->row1, row2->row3)
    DPP_STAGE(key, 0x143);  // row_bcast31          (lower32 -> upper32)

    const int buf = s & 1;
    if (lane == 63) red[buf][w] = key;
    __syncthreads();

    // depth-3 compare tree over 8 wave winners (broadcast LDS reads)
    unsigned long long kk[8];
#pragma unroll
    for (int i = 0; i < 8; ++i) kk[i] = red[buf][i];
#pragma unroll
    for (int st = 4; st >= 1; st >>= 1)
#pragma unroll
      for (int i = 0; i < 4; ++i)
        if (i < st && kk[i + st] > kk[i]) kk[i] = kk[i + st];

    const unsigned widx = ~(unsigned)(kk[0] & 0xffffffffull);
    const float4 wc = cxyz[widx];                   // one broadcast b128 read
    if (tid == 0) {
      smp[s * 3 + 0] = wc.x; smp[s * 3 + 1] = wc.y; smp[s * 3 + 2] = wc.z;
    }

    // fused md update + local argmax for next iteration
    bv = -INFINITY; bidx = 0;
#pragma unroll
    for (int j = 0; j < 16; ++j) {
      int i = tid + j * 512;
      float d = sqdist3(px[j], py[j], pz[j], wc.x, wc.y, wc.z);
      float nm = fminf(md[j], d);
      md[j] = nm;
      if (nm > bv) { bv = nm; bidx = i; }
    }
    // double-buffered red[]: one barrier per iteration is safe
  }
}

// ---------------------------------------------------------------------------
// 2) Point embedding: feats = sampled @ W_embed + b_embed    [B*M, 768]
// ---------------------------------------------------------------------------
__global__ void embed_kernel(const float* __restrict__ sampled,
                             const float* __restrict__ W,
                             const float* __restrict__ bias,
                             float* __restrict__ out) {
  int idx = blockIdx.x * blockDim.x + threadIdx.x;
  if (idx >= BMD) return;
  int d = idx % DIM;
  int bm = idx / DIM;
  float x = sampled[bm * 3 + 0], y = sampled[bm * 3 + 1], z = sampled[bm * 3 + 2];
  out[idx] = fmaf(z, W[2 * DIM + d], fmaf(y, W[DIM + d], fmaf(x, W[d], bias[d])));
}

// ---------------------------------------------------------------------------
// 3) kNN (k=8, incl. self) + edge = feat - mean(neighbor feats)
// ---------------------------------------------------------------------------
__global__ __launch_bounds__(256) void knn_edge_kernel(const float* __restrict__ sampled,
                                                       const float* __restrict__ feats,
                                                       float* __restrict__ edge) {
  const int bm = blockIdx.x;
  const int b = bm >> 10, m = bm & 1023;
  const float* sp = sampled + (size_t)b * MS * 3;
  const int t = threadIdx.x, lane = t & 63, wid = t >> 6;

  __shared__ float dist[MS];
  __shared__ float redv[4];
  __shared__ int   redi[4];
  __shared__ int   win[KNN];

  const float qx = sp[m * 3 + 0], qy = sp[m * 3 + 1], qz = sp[m * 3 + 2];
#pragma unroll
  for (int j = 0; j < 4; ++j) {
    int i = t + j * 256;
    dist[i] = sqdist3(sp[i * 3 + 0], sp[i * 3 + 1], sp[i * 3 + 2], qx, qy, qz);
  }
  __syncthreads();

  for (int it = 0; it < KNN; ++it) {
    float bv = dist[t]; int bi = t;
#pragma unroll
    for (int j = 1; j < 4; ++j) {
      int i = t + j * 256;
      float v = dist[i];
      if (v < bv || (v == bv && i < bi)) { bv = v; bi = i; }
    }
#pragma unroll
    for (int off = 32; off >= 1; off >>= 1) {
      float ov = __shfl_xor(bv, off);
      int   oi = __shfl_xor(bi, off);
      if (ov < bv || (ov == bv && oi < bi)) { bv = ov; bi = oi; }
    }
    if (lane == 0) { redv[wid] = bv; redi[wid] = bi; }
    __syncthreads();
    if (t == 0) {
      float wv = redv[0]; int wi = redi[0];
#pragma unroll
      for (int w = 1; w < 4; ++w) {
        float ov = redv[w]; int oi = redi[w];
        if (ov < wv || (ov == wv && oi < wi)) { wv = ov; wi = oi; }
      }
      win[it] = wi;
      dist[wi] = FLT_MAX;
    }
    __syncthreads();
  }

  const float* fb = feats + (size_t)b * MS * DIM;
  float* eb = edge + (size_t)b * MS * DIM;
  for (int d = t; d < DIM; d += 256) {
    float acc = 0.f;
#pragma unroll
    for (int i = 0; i < KNN; ++i) acc += fb[(size_t)win[i] * DIM + d];
    eb[(size_t)m * DIM + d] = fb[(size_t)m * DIM + d] - acc * 0.125f;
  }
}

// ---------------------------------------------------------------------------
// 4) fp32 tiled GEMM v2: C[4096,768] = A @ W + bias. 128x64 tile, 8x4 micro.
//    MODE 1: also += sampled@Ws + bs (final epilogue)
// ---------------------------------------------------------------------------
template <int MODE>
__global__ __launch_bounds__(256) void gemm_kernel(const float* __restrict__ A,
                                                   const float* __restrict__ W,
                                                   const float* __restrict__ bias,
                                                   float* __restrict__ C,
                                                   const float* __restrict__ sampled,
                                                   const float* __restrict__ Ws,
                                                   const float* __restrict__ bs) {
  __shared__ float As[16][132];   // [k][m], padded
  __shared__ float Bs[16][68];    // [k][n], padded

  const int t = threadIdx.x;
  const int tx = t & 15, ty = t >> 4;      // tx: n/4, ty: m/8
  const int rowBase = blockIdx.x * 128;
  const int nBase = blockIdx.y * 64;

  float c[8][4] = {};

  const int ar = t >> 1, ac8 = (t & 1) * 8;   // A: 128 rows x 16 k, 2 float4/thread
  const int br = t >> 4, bc4 = (t & 15) * 4;  // B: 16 k x 64 n, 1 float4/thread

  for (int k0 = 0; k0 < DIM; k0 += 16) {
    float4 a0 = *(const float4*)&A[(size_t)(rowBase + ar) * DIM + k0 + ac8];
    float4 a1 = *(const float4*)&A[(size_t)(rowBase + ar) * DIM + k0 + ac8 + 4];
    As[ac8 + 0][ar] = a0.x; As[ac8 + 1][ar] = a0.y;
    As[ac8 + 2][ar] = a0.z; As[ac8 + 3][ar] = a0.w;
    As[ac8 + 4][ar] = a1.x; As[ac8 + 5][ar] = a1.y;
    As[ac8 + 6][ar] = a1.z; As[ac8 + 7][ar] = a1.w;
    float4 wv = *(const float4*)&W[(size_t)(k0 + br) * DIM + nBase + bc4];
    *(float4*)&Bs[br][bc4] = wv;
    __syncthreads();
#pragma unroll
    for (int k = 0; k < 16; ++k) {
      float av[8], bv[4];
      *(float4*)&av[0] = *(const float4*)&As[k][ty * 8];
      *(float4*)&av[4] = *(const float4*)&As[k][ty * 8 + 4];
      *(float4*)bv = *(const float4*)&Bs[k][tx * 4];
#pragma unroll
      for (int i = 0; i < 8; ++i)
#pragma unroll
        for (int j = 0; j < 4; ++j)
          c[i][j] = fmaf(av[i], bv[j], c[i][j]);
    }
    __syncthreads();
  }

#pragma unroll
  for (int i = 0; i < 8; ++i) {
    int row = rowBase + ty * 8 + i;
#pragma unroll
    for (int j = 0; j < 4; ++j) {
      int n = nBase + tx * 4 + j;
      float v = c[i][j] + bias[n];
      if (MODE == 1) {
        const float* sp = sampled + (size_t)row * 3;
        float spt = fmaf(sp[2], Ws[2 * DIM + n], fmaf(sp[1], Ws[DIM + n], fmaf(sp[0], Ws[n], bs[n])));
        v += spt;
      }
      C[(size_t)row * DIM + n] = v;
    }
  }
}

// ---------------------------------------------------------------------------
// 5) Attention v2 (unchanged): 64-row tile, 4 waves, 4x4 register micro-tiles,
//    XOR-swizzled LDS, per-wave P buffer, 2 barriers/tile.
// ---------------------------------------------------------------------------
static __device__ __forceinline__ int lidx(int r, int c) {
  return r * 64 + (c ^ ((r & 7) << 2));
}

__global__ __launch_bounds__(256) void attn_kernel(const float* __restrict__ Q,
                                                   const float* __restrict__ K,
                                                   const float* __restrict__ V,
                                                   float* __restrict__ O) {
  const int nrt = MS / 64;                    // 16 row-tiles
  const int blk = blockIdx.x;                 // B*NH*nrt
  const int bh = blk / nrt, rt = blk % nrt;
  const int b = bh / NH, h = bh % NH;
  const int t = threadIdx.x, lane = t & 63, w = t >> 6;
  const int rg = lane >> 4, kg = lane & 15;

  __shared__ float Qs[64 * 64];
  __shared__ float Ks[64 * 64];
  __shared__ float Vs[64 * 64];
  __shared__ float Ps[4 * 16 * 64];           // per-wave private P

  const size_t base = (size_t)(b * MS) * DIM + (size_t)h * DHD;

#pragma unroll
  for (int i = 0; i < 4; ++i) {
    int f = t + i * 256;
    int r = f >> 4, c4 = (f & 15) * 4;
    *(float4*)&Qs[lidx(r, c4)] = *(const float4*)&Q[base + (size_t)(rt * 64 + r) * DIM + c4];
  }

  float m[4], l[4], o[4][4];
#pragma unroll
  for (int i = 0; i < 4; ++i) {
    m[i] = -INFINITY; l[i] = 0.f;
#pragma unroll
    for (int j = 0; j < 4; ++j) o[i][j] = 0.f;
  }

  const int lrow = w * 16 + rg * 4;
  float* Pw = &Ps[w * 16 * 64];

  for (int kt = 0; kt < nrt; ++kt) {
#pragma unroll
    for (int i = 0; i < 4; ++i) {
      int f = t + i * 256;
      int r = f >> 4, c4 = (f & 15) * 4;
      size_t g = base + (size_t)(kt * 64 + r) * DIM + c4;
      *(float4*)&Ks[lidx(r, c4)] = *(const float4*)&K[g];
      *(float4*)&Vs[lidx(r, c4)] = *(const float4*)&V[g];
    }
    __syncthreads();

    float s[4][4] = {};
#pragma unroll 8
    for (int d = 0; d < 64; ++d) {
      float a[4], bb[4];
#pragma unroll
      for (int i = 0; i < 4; ++i) a[i] = Qs[lidx(lrow + i, d)];
#pragma unroll
      for (int j = 0; j < 4; ++j) bb[j] = Ks[lidx(kg + 16 * j, d)];
#pragma unroll
      for (int i = 0; i < 4; ++i)
#pragma unroll
        for (int j = 0; j < 4; ++j) s[i][j] = fmaf(a[i], bb[j], s[i][j]);
    }

#pragma unroll
    for (int i = 0; i < 4; ++i) {
#pragma unroll
      for (int j = 0; j < 4; ++j) s[i][j] *= 0.125f;   // 1/sqrt(64)
      float mt = fmaxf(fmaxf(s[i][0], s[i][1]), fmaxf(s[i][2], s[i][3]));
#pragma unroll
      for (int off = 1; off < 16; off <<= 1) mt = fmaxf(mt, __shfl_xor(mt, off));
      float mn = fmaxf(m[i], mt);
      float corr = expf(m[i] - mn);
      float ps = 0.f;
#pragma unroll
      for (int j = 0; j < 4; ++j) { s[i][j] = expf(s[i][j] - mn); ps += s[i][j]; }
#pragma unroll
      for (int off = 1; off < 16; off <<= 1) ps += __shfl_xor(ps, off);
      l[i] = l[i] * corr + ps;
      m[i] = mn;
#pragma unroll
      for (int j = 0; j < 4; ++j) o[i][j] *= corr;
#pragma unroll
      for (int j = 0; j < 4; ++j) Pw[lidx(rg * 4 + i, kg + 16 * j)] = s[i][j];
    }

#pragma unroll 8
    for (int k = 0; k < 64; ++k) {
      float a[4], bb[4];
#pragma unroll
      for (int i = 0; i < 4; ++i) a[i] = Pw[lidx(rg * 4 + i, k)];
#pragma unroll
      for (int j = 0; j < 4; ++j) bb[j] = Vs[lidx(k, kg + 16 * j)];
#pragma unroll
      for (int i = 0; i < 4; ++i)
#pragma unroll
        for (int j = 0; j < 4; ++j) o[i][j] = fmaf(a[i], bb[j], o[i][j]);
    }
    __syncthreads();
  }

#pragma unroll
  for (int i = 0; i < 4; ++i) {
    int row = rt * 64 + lrow + i;
#pragma unroll
    for (int j = 0; j < 4; ++j)
      O[base + (size_t)row * DIM + kg + 16 * j] = o[i][j] / l[i];
  }
}

// ---------------------------------------------------------------------------
extern "C" void kernel_launch(void* const* d_in, const int* in_sizes, int n_in,
                              void* d_out, int out_size, void* d_ws, size_t ws_size,
                              hipStream_t stream) {
  const float* points  = (const float*)d_in[0];
  const float* W_embed = (const float*)d_in[1];
  const float* b_embed = (const float*)d_in[2];
  const float* Wq = (const float*)d_in[3];
  const float* bq = (const float*)d_in[4];
  const float* Wk = (const float*)d_in[5];
  const float* bk = (const float*)d_in[6];
  const float* Wv = (const float*)d_in[7];
  const float* bv = (const float*)d_in[8];
  const float* Wo = (const float*)d_in[9];
  const float* bo = (const float*)d_in[10];
  const float* Ws = (const float*)d_in[11];
  const float* bs = (const float*)d_in[12];

  float* ws = (float*)d_ws;
  float* sampled = ws;                 // B*M*3
  float* feats   = ws + 16384;
  float* edge    = feats + BMD;
  float* qb      = edge + BMD;
  float* kb      = qb + BMD;
  float* vb      = kb + BMD;
  float* ao      = vb + BMD;

  fps_kernel<<<BB, 512, 0, stream>>>(points, sampled);
  embed_kernel<<<(BMD + 255) / 256, 256, 0, stream>>>(sampled, W_embed, b_embed, feats);
  knn_edge_kernel<<<BB * MS, 256, 0, stream>>>(sampled, feats, edge);

  dim3 ggrid(4096 / 128, DIM / 64);
  gemm_kernel<0><<<ggrid, 256, 0, stream>>>(edge, Wq, bq, qb, nullptr, nullptr, nullptr);
  gemm_kernel<0><<<ggrid, 256, 0, stream>>>(edge, Wk, bk, kb, nullptr, nullptr, nullptr);
  gemm_kernel<0><<<ggrid, 256, 0, stream>>>(edge, Wv, bv, vb, nullptr, nullptr, nullptr);

  attn_kernel<<<BB * NH * (MS / 64), 256, 0, stream>>>(qb, kb, vb, ao);

  gemm_kernel<1><<<ggrid, 256, 0, stream>>>(ao, Wo, bo, (float*)d_out, sampled, Ws, bs);
}

// Round 15
// 1746.382 us; speedup vs baseline: 3.1597x; 1.0211x over previous
//
#include <hip/hip_runtime.h>
#include <float.h>
#include <math.h>

#define BB   4
#define NPTS 8192
#define MS   1024
#define DIM  768
#define NH   12
#define DHD  64
#define KNN  8
#define BMD  (BB*MS*DIM)

typedef float v2f __attribute__((ext_vector_type(2)));

static __device__ __forceinline__ float sqdist3(float ax, float ay, float az,
                                                float bx, float by, float bz) {
  float dx = __fsub_rn(ax, bx);
  float dy = __fsub_rn(ay, by);
  float dz = __fsub_rn(az, bz);
  // match XLA: elementwise square (mul), then sequential sum — no fma contraction
  return __fadd_rn(__fadd_rn(__fmul_rn(dx, dx), __fmul_rn(dy, dy)), __fmul_rn(dz, dz));
}

// ---------------------------------------------------------------------------
// 1) FPS v5: one block/batch, 512 threads, 16 pts/thread held as 8x float2.
//    R13 counters: VALU-issue-bound (83% busy on the 4 active CUs). v5 packs
//    the distance math into v_pk_{add,mul}_f32 (2 pts/inst) via ext_vector
//    float2 + `fp contract(off)` (keeps mul-then-add exact => bit-identical
//    selection vs XLA; pair order even=.x preserves lowest-index tie-break).
//    Reduce: 6-stage DPP merge on packed u64 (distbits<<32 | ~idx), 8-entry
//    cross-wave LDS tree, coords via one broadcast ds_read_b128.
// ---------------------------------------------------------------------------
#define DPP_STAGE(key, ctrl)                                                   \
  {                                                                            \
    unsigned hi_ = (unsigned)((key) >> 32), lo_ = (unsigned)(key);             \
    unsigned nhi_ = (unsigned)__builtin_amdgcn_update_dpp(                     \
        (int)hi_, (int)hi_, (ctrl), 0xf, 0xf, false);                          \
    unsigned nlo_ = (unsigned)__builtin_amdgcn_update_dpp(                     \
        (int)lo_, (int)lo_, (ctrl), 0xf, 0xf, false);                          \
    unsigned long long nk_ = ((unsigned long long)nhi_ << 32) | nlo_;          \
    if (nk_ > (key)) (key) = nk_;                                              \
  }

__global__ __launch_bounds__(512, 1) void fps_kernel(const float* __restrict__ points,
                                                     float* __restrict__ sampled) {
#pragma clang fp contract(off)
  const int b = blockIdx.x;
  const float* pts = points + (size_t)b * NPTS * 3;
  float* smp = sampled + (size_t)b * MS * 3;
  const int tid = threadIdx.x;
  const int lane = tid & 63, w = tid >> 6;

  __shared__ float4 cxyz[NPTS];                     // 128 KB coord cache
  __shared__ unsigned long long red[2][8];

  v2f px[8], py[8], pz[8], md[8];
  const float qx0 = pts[0], qy0 = pts[1], qz0 = pts[2];

  float bv = -INFINITY;
  int bidx = 0;
#pragma unroll
  for (int j = 0; j < 8; ++j) {
    int i0 = 2 * tid + j * 1024;                    // pair (i0, i0+1); even=.x
    float x0 = pts[i0 * 3 + 0], y0 = pts[i0 * 3 + 1], z0 = pts[i0 * 3 + 2];
    float x1 = pts[i0 * 3 + 3], y1 = pts[i0 * 3 + 4], z1 = pts[i0 * 3 + 5];
    px[j] = (v2f){x0, x1}; py[j] = (v2f){y0, y1}; pz[j] = (v2f){z0, z1};
    cxyz[i0]     = make_float4(x0, y0, z0, 0.f);
    cxyz[i0 + 1] = make_float4(x1, y1, z1, 0.f);
    v2f dx = px[j] - qx0, dy = py[j] - qy0, dz = pz[j] - qz0;
    v2f d  = (dx * dx + dy * dy) + dz * dz;         // contract(off): mul+add exact
    md[j] = d;
    if (d.x > bv) { bv = d.x; bidx = i0; }          // .x first => lower idx on tie
    if (d.y > bv) { bv = d.y; bidx = i0 + 1; }
  }
  if (tid == 0) { smp[0] = qx0; smp[1] = qy0; smp[2] = qz0; }
  __syncthreads();

  for (int s = 1; s < MS; ++s) {
    // pack (dist, ~idx); non-negative float bits compare as uint
    unsigned long long key =
        ((unsigned long long)__float_as_uint(bv) << 32) |
        (unsigned)(~(unsigned)bidx);

    // 6-stage DPP merge network -> lane63 = wave winner
    DPP_STAGE(key, 0xB1);   // quad_perm [1,0,3,2]  (xor 1)
    DPP_STAGE(key, 0x4E);   // quad_perm [2,3,0,1]  (xor 2)
    DPP_STAGE(key, 0x141);  // row_half_mirror      (xor 7 within 8)
    DPP_STAGE(key, 0x140);  // row_mirror           (xor 15 within 16)
    DPP_STAGE(key, 0x142);  // row_bcast15          (row0->row1, row2->row3)
    DPP_STAGE(key, 0x143);  // row_bcast31          (lower32 -> upper32)

    const int buf = s & 1;
    if (lane == 63) red[buf][w] = key;
    __syncthreads();

    // depth-3 compare tree over 8 wave winners (broadcast LDS reads)
    unsigned long long kk[8];
#pragma unroll
    for (int i = 0; i < 8; ++i) kk[i] = red[buf][i];
#pragma unroll
    for (int st = 4; st >= 1; st >>= 1)
#pragma unroll
      for (int i = 0; i < 4; ++i)
        if (i < st && kk[i + st] > kk[i]) kk[i] = kk[i + st];

    const unsigned widx = ~(unsigned)(kk[0] & 0xffffffffull);
    const float4 wc = cxyz[widx];                   // one broadcast b128 read
    if (tid == 0) {
      smp[s * 3 + 0] = wc.x; smp[s * 3 + 1] = wc.y; smp[s * 3 + 2] = wc.z;
    }

    // fused packed md update + local argmax for next iteration
    bv = -INFINITY; bidx = 0;
#pragma unroll
    for (int j = 0; j < 8; ++j) {
      int i0 = 2 * tid + j * 1024;
      v2f dx = px[j] - wc.x, dy = py[j] - wc.y, dz = pz[j] - wc.z;
      v2f d  = (dx * dx + dy * dy) + dz * dz;       // v_pk_mul/add, no fma
      v2f nm = __builtin_elementwise_min(md[j], d); // 2x v_min_f32
      md[j] = nm;
      if (nm.x > bv) { bv = nm.x; bidx = i0; }
      if (nm.y > bv) { bv = nm.y; bidx = i0 + 1; }
    }
    // double-buffered red[]: one barrier per iteration is safe
  }
}

// ---------------------------------------------------------------------------
// 2) Point embedding: feats = sampled @ W_embed + b_embed    [B*M, 768]
// ---------------------------------------------------------------------------
__global__ void embed_kernel(const float* __restrict__ sampled,
                             const float* __restrict__ W,
                             const float* __restrict__ bias,
                             float* __restrict__ out) {
  int idx = blockIdx.x * blockDim.x + threadIdx.x;
  if (idx >= BMD) return;
  int d = idx % DIM;
  int bm = idx / DIM;
  float x = sampled[bm * 3 + 0], y = sampled[bm * 3 + 1], z = sampled[bm * 3 + 2];
  out[idx] = fmaf(z, W[2 * DIM + d], fmaf(y, W[DIM + d], fmaf(x, W[d], bias[d])));
}

// ---------------------------------------------------------------------------
// 3) kNN (k=8, incl. self) + edge = feat - mean(neighbor feats)
// ---------------------------------------------------------------------------
__global__ __launch_bounds__(256) void knn_edge_kernel(const float* __restrict__ sampled,
                                                       const float* __restrict__ feats,
                                                       float* __restrict__ edge) {
  const int bm = blockIdx.x;
  const int b = bm >> 10, m = bm & 1023;
  const float* sp = sampled + (size_t)b * MS * 3;
  const int t = threadIdx.x, lane = t & 63, wid = t >> 6;

  __shared__ float dist[MS];
  __shared__ float redv[4];
  __shared__ int   redi[4];
  __shared__ int   win[KNN];

  const float qx = sp[m * 3 + 0], qy = sp[m * 3 + 1], qz = sp[m * 3 + 2];
#pragma unroll
  for (int j = 0; j < 4; ++j) {
    int i = t + j * 256;
    dist[i] = sqdist3(sp[i * 3 + 0], sp[i * 3 + 1], sp[i * 3 + 2], qx, qy, qz);
  }
  __syncthreads();

  for (int it = 0; it < KNN; ++it) {
    float bv = dist[t]; int bi = t;
#pragma unroll
    for (int j = 1; j < 4; ++j) {
      int i = t + j * 256;
      float v = dist[i];
      if (v < bv || (v == bv && i < bi)) { bv = v; bi = i; }
    }
#pragma unroll
    for (int off = 32; off >= 1; off >>= 1) {
      float ov = __shfl_xor(bv, off);
      int   oi = __shfl_xor(bi, off);
      if (ov < bv || (ov == bv && oi < bi)) { bv = ov; bi = oi; }
    }
    if (lane == 0) { redv[wid] = bv; redi[wid] = bi; }
    __syncthreads();
    if (t == 0) {
      float wv = redv[0]; int wi = redi[0];
#pragma unroll
      for (int w = 1; w < 4; ++w) {
        float ov = redv[w]; int oi = redi[w];
        if (ov < wv || (ov == wv && oi < wi)) { wv = ov; wi = oi; }
      }
      win[it] = wi;
      dist[wi] = FLT_MAX;
    }
    __syncthreads();
  }

  const float* fb = feats + (size_t)b * MS * DIM;
  float* eb = edge + (size_t)b * MS * DIM;
  for (int d = t; d < DIM; d += 256) {
    float acc = 0.f;
#pragma unroll
    for (int i = 0; i < KNN; ++i) acc += fb[(size_t)win[i] * DIM + d];
    eb[(size_t)m * DIM + d] = fb[(size_t)m * DIM + d] - acc * 0.125f;
  }
}

// ---------------------------------------------------------------------------
// 4) fp32 tiled GEMM v2: C[4096,768] = A @ W + bias. 128x64 tile, 8x4 micro.
//    MODE 1: also += sampled@Ws + bs (final epilogue)
// ---------------------------------------------------------------------------
template <int MODE>
__global__ __launch_bounds__(256) void gemm_kernel(const float* __restrict__ A,
                                                   const float* __restrict__ W,
                                                   const float* __restrict__ bias,
                                                   float* __restrict__ C,
                                                   const float* __restrict__ sampled,
                                                   const float* __restrict__ Ws,
                                                   const float* __restrict__ bs) {
  __shared__ float As[16][132];   // [k][m], padded
  __shared__ float Bs[16][68];    // [k][n], padded

  const int t = threadIdx.x;
  const int tx = t & 15, ty = t >> 4;      // tx: n/4, ty: m/8
  const int rowBase = blockIdx.x * 128;
  const int nBase = blockIdx.y * 64;

  float c[8][4] = {};

  const int ar = t >> 1, ac8 = (t & 1) * 8;   // A: 128 rows x 16 k, 2 float4/thread
  const int br = t >> 4, bc4 = (t & 15) * 4;  // B: 16 k x 64 n, 1 float4/thread

  for (int k0 = 0; k0 < DIM; k0 += 16) {
    float4 a0 = *(const float4*)&A[(size_t)(rowBase + ar) * DIM + k0 + ac8];
    float4 a1 = *(const float4*)&A[(size_t)(rowBase + ar) * DIM + k0 + ac8 + 4];
    As[ac8 + 0][ar] = a0.x; As[ac8 + 1][ar] = a0.y;
    As[ac8 + 2][ar] = a0.z; As[ac8 + 3][ar] = a0.w;
    As[ac8 + 4][ar] = a1.x; As[ac8 + 5][ar] = a1.y;
    As[ac8 + 6][ar] = a1.z; As[ac8 + 7][ar] = a1.w;
    float4 wv = *(const float4*)&W[(size_t)(k0 + br) * DIM + nBase + bc4];
    *(float4*)&Bs[br][bc4] = wv;
    __syncthreads();
#pragma unroll
    for (int k = 0; k < 16; ++k) {
      float av[8], bv[4];
      *(float4*)&av[0] = *(const float4*)&As[k][ty * 8];
      *(float4*)&av[4] = *(const float4*)&As[k][ty * 8 + 4];
      *(float4*)bv = *(const float4*)&Bs[k][tx * 4];
#pragma unroll
      for (int i = 0; i < 8; ++i)
#pragma unroll
        for (int j = 0; j < 4; ++j)
          c[i][j] = fmaf(av[i], bv[j], c[i][j]);
    }
    __syncthreads();
  }

#pragma unroll
  for (int i = 0; i < 8; ++i) {
    int row = rowBase + ty * 8 + i;
#pragma unroll
    for (int j = 0; j < 4; ++j) {
      int n = nBase + tx * 4 + j;
      float v = c[i][j] + bias[n];
      if (MODE == 1) {
        const float* sp = sampled + (size_t)row * 3;
        float spt = fmaf(sp[2], Ws[2 * DIM + n], fmaf(sp[1], Ws[DIM + n], fmaf(sp[0], Ws[n], bs[n])));
        v += spt;
      }
      C[(size_t)row * DIM + n] = v;
    }
  }
}

// ---------------------------------------------------------------------------
// 5) Attention v2 (unchanged): 64-row tile, 4 waves, 4x4 register micro-tiles,
//    XOR-swizzled LDS, per-wave P buffer, 2 barriers/tile.
// ---------------------------------------------------------------------------
static __device__ __forceinline__ int lidx(int r, int c) {
  return r * 64 + (c ^ ((r & 7) << 2));
}

__global__ __launch_bounds__(256) void attn_kernel(const float* __restrict__ Q,
                                                   const float* __restrict__ K,
                                                   const float* __restrict__ V,
                                                   float* __restrict__ O) {
  const int nrt = MS / 64;                    // 16 row-tiles
  const int blk = blockIdx.x;                 // B*NH*nrt
  const int bh = blk / nrt, rt = blk % nrt;
  const int b = bh / NH, h = bh % NH;
  const int t = threadIdx.x, lane = t & 63, w = t >> 6;
  const int rg = lane >> 4, kg = lane & 15;

  __shared__ float Qs[64 * 64];
  __shared__ float Ks[64 * 64];
  __shared__ float Vs[64 * 64];
  __shared__ float Ps[4 * 16 * 64];           // per-wave private P

  const size_t base = (size_t)(b * MS) * DIM + (size_t)h * DHD;

#pragma unroll
  for (int i = 0; i < 4; ++i) {
    int f = t + i * 256;
    int r = f >> 4, c4 = (f & 15) * 4;
    *(float4*)&Qs[lidx(r, c4)] = *(const float4*)&Q[base + (size_t)(rt * 64 + r) * DIM + c4];
  }

  float m[4], l[4], o[4][4];
#pragma unroll
  for (int i = 0; i < 4; ++i) {
    m[i] = -INFINITY; l[i] = 0.f;
#pragma unroll
    for (int j = 0; j < 4; ++j) o[i][j] = 0.f;
  }

  const int lrow = w * 16 + rg * 4;
  float* Pw = &Ps[w * 16 * 64];

  for (int kt = 0; kt < nrt; ++kt) {
#pragma unroll
    for (int i = 0; i < 4; ++i) {
      int f = t + i * 256;
      int r = f >> 4, c4 = (f & 15) * 4;
      size_t g = base + (size_t)(kt * 64 + r) * DIM + c4;
      *(float4*)&Ks[lidx(r, c4)] = *(const float4*)&K[g];
      *(float4*)&Vs[lidx(r, c4)] = *(const float4*)&V[g];
    }
    __syncthreads();

    float s[4][4] = {};
#pragma unroll 8
    for (int d = 0; d < 64; ++d) {
      float a[4], bb[4];
#pragma unroll
      for (int i = 0; i < 4; ++i) a[i] = Qs[lidx(lrow + i, d)];
#pragma unroll
      for (int j = 0; j < 4; ++j) bb[j] = Ks[lidx(kg + 16 * j, d)];
#pragma unroll
      for (int i = 0; i < 4; ++i)
#pragma unroll
        for (int j = 0; j < 4; ++j) s[i][j] = fmaf(a[i], bb[j], s[i][j]);
    }

#pragma unroll
    for (int i = 0; i < 4; ++i) {
#pragma unroll
      for (int j = 0; j < 4; ++j) s[i][j] *= 0.125f;   // 1/sqrt(64)
      float mt = fmaxf(fmaxf(s[i][0], s[i][1]), fmaxf(s[i][2], s[i][3]));
#pragma unroll
      for (int off = 1; off < 16; off <<= 1) mt = fmaxf(mt, __shfl_xor(mt, off));
      float mn = fmaxf(m[i], mt);
      float corr = expf(m[i] - mn);
      float ps = 0.f;
#pragma unroll
      for (int j = 0; j < 4; ++j) { s[i][j] = expf(s[i][j] - mn); ps += s[i][j]; }
#pragma unroll
      for (int off = 1; off < 16; off <<= 1) ps += __shfl_xor(ps, off);
      l[i] = l[i] * corr + ps;
      m[i] = mn;
#pragma unroll
      for (int j = 0; j < 4; ++j) o[i][j] *= corr;
#pragma unroll
      for (int j = 0; j < 4; ++j) Pw[lidx(rg * 4 + i, kg + 16 * j)] = s[i][j];
    }

#pragma unroll 8
    for (int k = 0; k < 64; ++k) {
      float a[4], bb[4];
#pragma unroll
      for (int i = 0; i < 4; ++i) a[i] = Pw[lidx(rg * 4 + i, k)];
#pragma unroll
      for (int j = 0; j < 4; ++j) bb[j] = Vs[lidx(k, kg + 16 * j)];
#pragma unroll
      for (int i = 0; i < 4; ++i)
#pragma unroll
        for (int j = 0; j < 4; ++j) o[i][j] = fmaf(a[i], bb[j], o[i][j]);
    }
    __syncthreads();
  }

#pragma unroll
  for (int i = 0; i < 4; ++i) {
    int row = rt * 64 + lrow + i;
#pragma unroll
    for (int j = 0; j < 4; ++j)
      O[base + (size_t)row * DIM + kg + 16 * j] = o[i][j] / l[i];
  }
}

// ---------------------------------------------------------------------------
extern "C" void kernel_launch(void* const* d_in, const int* in_sizes, int n_in,
                              void* d_out, int out_size, void* d_ws, size_t ws_size,
                              hipStream_t stream) {
  const float* points  = (const float*)d_in[0];
  const float* W_embed = (const float*)d_in[1];
  const float* b_embed = (const float*)d_in[2];
  const float* Wq = (const float*)d_in[3];
  const float* bq = (const float*)d_in[4];
  const float* Wk = (const float*)d_in[5];
  const float* bk = (const float*)d_in[6];
  const float* Wv = (const float*)d_in[7];
  const float* bv = (const float*)d_in[8];
  const float* Wo = (const float*)d_in[9];
  const float* bo = (const float*)d_in[10];
  const float* Ws = (const float*)d_in[11];
  const float* bs = (const float*)d_in[12];

  float* ws = (float*)d_ws;
  float* sampled = ws;                 // B*M*3
  float* feats   = ws + 16384;
  float* edge    = feats + BMD;
  float* qb      = edge + BMD;
  float* kb      = qb + BMD;
  float* vb      = kb + BMD;
  float* ao      = vb + BMD;

  fps_kernel<<<BB, 512, 0, stream>>>(points, sampled);
  embed_kernel<<<(BMD + 255) / 256, 256, 0, stream>>>(sampled, W_embed, b_embed, feats);
  knn_edge_kernel<<<BB * MS, 256, 0, stream>>>(sampled, feats, edge);

  dim3 ggrid(4096 / 128, DIM / 64);
  gemm_kernel<0><<<ggrid, 256, 0, stream>>>(edge, Wq, bq, qb, nullptr, nullptr, nullptr);
  gemm_kernel<0><<<ggrid, 256, 0, stream>>>(edge, Wk, bk, kb, nullptr, nullptr, nullptr);
  gemm_kernel<0><<<ggrid, 256, 0, stream>>>(edge, Wv, bv, vb, nullptr, nullptr, nullptr);

  attn_kernel<<<BB * NH * (MS / 64), 256, 0, stream>>>(qb, kb, vb, ao);

  gemm_kernel<1><<<ggrid, 256, 0, stream>>>(ao, Wo, bo, (float*)d_out, sampled, Ws, bs);
}